// Round 3
// baseline (171.669 us; speedup 1.0000x reference)
//
#include <hip/hip_runtime.h>
#include <hip/hip_bf16.h>
#include <math.h>

// TinyMoE: out = sum_e softmax(x@Wr)[e] * (gelu(x@w1[e]+b1[e]) @ w2[e] + b2[e])
// Two dense GEMMs: [32768x512]@[512x256] -> gelu/scale -> @[256x512(+b2 rows)]
// bf16 MFMA (16x16x32), fp32 router/softmax/gelu.
// v4: 32 tokens per WG (4 waves, 256 thr), __launch_bounds__(256,3) -> 3 blocks/CU
//     (12 waves/CU) with a 170-reg/wave budget: the max occupancy that fits this
//     kernel's ~140-reg demand WITHOUT spilling (v2/v3 post-mortem: 4 waves/SIMD
//     = 128-reg budget forces a 64/64 arch/AGPR split -> scratch spill, +18MB HBM).
//     Router folded into GEMM1 K-loop, in-register softmax via shfl_xor; 3 barriers.

typedef short v8s __attribute__((ext_vector_type(8)));
typedef float v4f __attribute__((ext_vector_type(4)));

#define XS 520   // X LDS row stride (bf16 elems): 512 + 8 pad
#define HS 296   // H LDS row stride: 288 (=256 + 4 b2-weight rows + 28 zero pad) + 8 pad

__device__ __forceinline__ unsigned short f2bf(float f) {
    unsigned int u = __builtin_bit_cast(unsigned int, f);
    u += 0x7fffu + ((u >> 16) & 1u);
    return (unsigned short)(u >> 16);
}

// ---- prep: pack weights into bf16 MFMA B-fragment layout in workspace ----
// Block = 16(N) x 32(K) bf16, stored as [n_local*32 + k_local], 512 elems = 1KB.
// Lane l of a wave reads 16B at ((l&15)*32 + (l>>4)*8)*2 -> B[k][n], n=l&15, k=(l>>4)*8+j.
__global__ void moe_prep(const float* __restrict__ w1,   // (4,512,64)
                         const float* __restrict__ w2,   // (4,64,512)
                         const float* __restrict__ b2,   // (4,512)
                         const float* __restrict__ rw,   // (512,4)
                         unsigned short* __restrict__ w1p,
                         unsigned short* __restrict__ w2p,
                         unsigned short* __restrict__ rp) {
    int idx = blockIdx.x * 256 + threadIdx.x;
    if (idx < 131072) {
        // W1' [K=512][N=256], block = kb*16 + cb
        int block = idx >> 9, within = idx & 511;
        int kb = block >> 4, cb = block & 15;
        int n = within >> 5, kl = within & 31;
        int k = kb * 32 + kl;
        int col = cb * 16 + n;          // col in [0,256): e = col>>6, h = col&63
        int e = col >> 6, h = col & 63;
        w1p[idx] = f2bf(w1[(e * 512 + k) * 64 + h]);
    } else if (idx < 131072 + 147456) {
        // W2' [Kpad=288][N=512], block = kb*32 + cb. k in [256,260) = b2 rows, >=260 zero.
        int op = idx - 131072;
        int block = op >> 9, within = op & 511;
        int kb = block >> 5, cb = block & 31;
        int n = within >> 5, kl = within & 31;
        int k = kb * 32 + kl;
        int d = cb * 16 + n;
        float v = 0.f;
        if (k < 256) {
            int e = k >> 6, h = k & 63;
            v = w2[(e * 64 + h) * 512 + d];
        } else if (k < 260) {
            v = b2[(k - 256) * 512 + d];
        }
        w2p[op] = f2bf(v);
    } else if (idx < 131072 + 147456 + 8192) {
        // router W [K=512][N=16] (cols >=4 zero), block = kb
        int op = idx - (131072 + 147456);
        int kb = op >> 9, within = op & 511;
        int n = within >> 5, kl = within & 31;
        int k = kb * 32 + kl;
        float v = (n < 4) ? rw[k * 4 + n] : 0.f;
        rp[op] = f2bf(v);
    }
}

// ---- main fused kernel ----
__global__ __launch_bounds__(256, 3)
void moe_main(const float* __restrict__ x,
              const float* __restrict__ rb,
              const float* __restrict__ b1,
              const unsigned short* __restrict__ w1p,
              const unsigned short* __restrict__ w2p,
              const unsigned short* __restrict__ rp,
              float* __restrict__ out) {
    // X tile [32][XS] bf16 = 33280 B; H tile [32][HS] aliases it after GEMM1.
    __shared__ __align__(16) unsigned short lx[32 * XS];
    __shared__ float lw[32 * 4];

    const int tid  = threadIdx.x;
    const int lane = tid & 63, wv = tid >> 6;
    const int lr = lane & 15, lq = lane >> 4;   // A: m=lr, k=lq*8+j ; B: n=lr ; C: col=lr, row=lq*4+r
    const long t0 = (long)blockIdx.x * 32;

    // ---- phase 0: stage X tile (fp32 global -> bf16 LDS) ----
    const float4* xt = (const float4*)(x + t0 * 512);
    #pragma unroll
    for (int it = 0; it < 16; ++it) {
        int F = it * 256 + tid;            // float4 index in 32x512 tile
        int row = F >> 7, c4 = F & 127;
        float4 v = xt[F];
        unsigned int p0 = (unsigned int)f2bf(v.x) | ((unsigned int)f2bf(v.y) << 16);
        unsigned int p1 = (unsigned int)f2bf(v.z) | ((unsigned int)f2bf(v.w) << 16);
        *(uint2*)&lx[row * XS + c4 * 4] = make_uint2(p0, p1);
    }
    __syncthreads();

    // ---- phase 1: GEMM1  C1[32][256] = X @ W1'; wave w owns cols [64w,64w+64) = expert w.
    //      Router logits computed redundantly per wave (extra 16-wide B frag from rp). ----
    v4f acc1[2][4];
    v4f accR[2];
    #pragma unroll
    for (int mt = 0; mt < 2; ++mt) {
        accR[mt][0] = accR[mt][1] = accR[mt][2] = accR[mt][3] = 0.f;
        #pragma unroll
        for (int nt = 0; nt < 4; ++nt)
            acc1[mt][nt][0] = acc1[mt][nt][1] = acc1[mt][nt][2] = acc1[mt][nt][3] = 0.f;
    }

    for (int kb = 0; kb < 16; ++kb) {
        v8s a[2], b[4], br;
        #pragma unroll
        for (int mt = 0; mt < 2; ++mt)
            a[mt] = *(const v8s*)(const void*)&lx[(16 * mt + lr) * XS + kb * 32 + lq * 8];
        #pragma unroll
        for (int nt = 0; nt < 4; ++nt)
            b[nt] = *(const v8s*)(const void*)&w1p[(size_t)(kb * 16 + wv * 4 + nt) * 512 + lr * 32 + lq * 8];
        br = *(const v8s*)(const void*)&rp[kb * 512 + lr * 32 + lq * 8];
        #pragma unroll
        for (int mt = 0; mt < 2; ++mt) {
            #pragma unroll
            for (int nt = 0; nt < 4; ++nt)
                acc1[mt][nt] = __builtin_amdgcn_mfma_f32_16x16x32_bf16(a[mt], b[nt], acc1[mt][nt], 0, 0, 0);
            accR[mt] = __builtin_amdgcn_mfma_f32_16x16x32_bf16(a[mt], br, accR[mt], 0, 0, 0);
        }
    }

    // ---- in-register softmax over experts (lanes lr=0..3 hold experts 0..3 per token) ----
    // accR[mt][r] = logit(row = 16mt + lq*4 + r, e = lr)
    float wreg[2][4];   // softmax weight, valid in lanes lr<4
    {
        float rbv = rb[lane & 3];
        #pragma unroll
        for (int mt = 0; mt < 2; ++mt)
            #pragma unroll
            for (int r = 0; r < 4; ++r) {
                float v = accR[mt][r] + rbv;
                float m = fmaxf(v, __shfl_xor(v, 1));
                m = fmaxf(m, __shfl_xor(m, 2));
                float e = expf(v - m);
                float s = e + __shfl_xor(e, 1);
                s += __shfl_xor(s, 2);
                wreg[mt][r] = e / s;
            }
    }
    // wave 0 publishes weights for the H router-weight columns
    if (wv == 0 && lr < 4) {
        #pragma unroll
        for (int mt = 0; mt < 2; ++mt)
            #pragma unroll
            for (int r = 0; r < 4; ++r)
                lw[(16 * mt + lq * 4 + r) * 4 + lr] = wreg[mt][r];
    }
    // each thread gathers the weight of ITS wave's expert for its C rows
    float wt[2][4];
    #pragma unroll
    for (int mt = 0; mt < 2; ++mt)
        #pragma unroll
        for (int r = 0; r < 4; ++r)
            wt[mt][r] = __shfl(wreg[mt][r], (lane & 48) | wv);

    __syncthreads();   // all waves done reading X; lx may now be overwritten by H; lw visible

    // ---- epilogue: gelu(v+b1)*router_weight -> bf16 H[32][288] ----
    {
        float b1v[4];
        #pragma unroll
        for (int nt = 0; nt < 4; ++nt) b1v[nt] = b1[wv * 64 + nt * 16 + lr];
        #pragma unroll
        for (int mt = 0; mt < 2; ++mt) {
            #pragma unroll
            for (int r = 0; r < 4; ++r) {
                int row = 16 * mt + lq * 4 + r;
                #pragma unroll
                for (int nt = 0; nt < 4; ++nt) {
                    float v = acc1[mt][nt][r] + b1v[nt];
                    float g = 0.5f * v * (1.f + erff(v * 0.70710678118f)) * wt[mt][r];
                    lx[row * HS + wv * 64 + nt * 16 + lr] = f2bf(g);
                }
            }
        }
        // append router-weight cols (k=256..259) and zero pad (260..287)
        if (tid < 128) {
            int r = tid >> 2, e = tid & 3;
            lx[r * HS + 256 + e] = f2bf(lw[tid]);
            #pragma unroll
            for (int i = 0; i < 7; ++i)
                lx[r * HS + 260 + e + 4 * i] = 0;
        }
    }
    __syncthreads();

    // ---- phase 3: GEMM2  OUT[32][512] = H[32][288] @ W2'; wave w owns cols [128w,128w+128) ----
    v4f acc2[2][8];
    #pragma unroll
    for (int mt = 0; mt < 2; ++mt)
        #pragma unroll
        for (int nt = 0; nt < 8; ++nt)
            acc2[mt][nt][0] = acc2[mt][nt][1] = acc2[mt][nt][2] = acc2[mt][nt][3] = 0.f;

    for (int kb = 0; kb < 9; ++kb) {
        v8s a[2], b[8];
        #pragma unroll
        for (int mt = 0; mt < 2; ++mt)
            a[mt] = *(const v8s*)(const void*)&lx[(16 * mt + lr) * HS + kb * 32 + lq * 8];
        #pragma unroll
        for (int nt = 0; nt < 8; ++nt)
            b[nt] = *(const v8s*)(const void*)&w2p[(size_t)(kb * 32 + wv * 8 + nt) * 512 + lr * 32 + lq * 8];
        #pragma unroll
        for (int mt = 0; mt < 2; ++mt)
            #pragma unroll
            for (int nt = 0; nt < 8; ++nt)
                acc2[mt][nt] = __builtin_amdgcn_mfma_f32_16x16x32_bf16(a[mt], b[nt], acc2[mt][nt], 0, 0, 0);
    }

    float* ot = out + t0 * 512;
    #pragma unroll
    for (int mt = 0; mt < 2; ++mt)
        #pragma unroll
        for (int nt = 0; nt < 8; ++nt)
            #pragma unroll
            for (int r = 0; r < 4; ++r) {
                int row = 16 * mt + lq * 4 + r;
                int col = 128 * wv + 16 * nt + lr;
                ot[row * 512 + col] = acc2[mt][nt][r];
            }
}

extern "C" void kernel_launch(void* const* d_in, const int* in_sizes, int n_in,
                              void* d_out, int out_size, void* d_ws, size_t ws_size,
                              hipStream_t stream) {
    const float* x  = (const float*)d_in[0];
    const float* rw = (const float*)d_in[1];
    const float* rb = (const float*)d_in[2];
    const float* w1 = (const float*)d_in[3];
    const float* b1 = (const float*)d_in[4];
    const float* w2 = (const float*)d_in[5];
    const float* b2 = (const float*)d_in[6];

    unsigned short* w1p = (unsigned short*)d_ws;      // 131072 elems
    unsigned short* w2p = w1p + 131072;               // 147456 elems
    unsigned short* rp  = w2p + 147456;               // 8192 elems  (total ~573 KB)

    moe_prep<<<1120, 256, 0, stream>>>(w1, w2, b2, rw, w1p, w2p, rp);
    moe_main<<<1024, 256, 0, stream>>>(x, rb, b1, w1p, w2p, rp, (float*)d_out);
}

// Round 4
// 144.637 us; speedup vs baseline: 1.1869x; 1.1869x over previous
//
#include <hip/hip_runtime.h>
#include <hip/hip_bf16.h>
#include <math.h>

// TinyMoE: out = sum_e softmax(x@Wr)[e] * (gelu(x@w1[e]+b1[e]) @ w2[e] + b2[e])
// Two dense GEMMs: [32768x512]@[512x256] -> gelu/scale -> @[256x512(+b2 rows)]
// bf16 MFMA (16x16x32), fp32 router/softmax/gelu.
// v5: back to the proven v1 geometry (64 tokens/WG, 4 waves, 2 blocks/CU, no spill).
//     v2-v4 showed runtime tracks per-wave MFMA density, not occupancy (4 waves/SIMD
//     spills; 32-token tiles halve ILP). Changes vs v1:
//       - router folded into GEMM1 K-loop (wave w does its 16 rows, +1 MFMA/kb),
//         in-register softmax via shfl_xor  -> removes 2 barriers + serial phase
//       - X staging split by K-half: cols 256..511 staged DURING GEMM1 kb 0..7
//         (writes touch only the not-yet-read half; T14 issue-early pattern)

typedef short v8s __attribute__((ext_vector_type(8)));
typedef float v4f __attribute__((ext_vector_type(4)));

#define XS 520   // X LDS row stride (bf16 elems): 512 + 8 pad
#define HS 296   // H LDS row stride: 288 (=256 + 4 b2-weight rows + 28 zero pad) + 8 pad

__device__ __forceinline__ unsigned short f2bf(float f) {
    unsigned int u = __builtin_bit_cast(unsigned int, f);
    u += 0x7fffu + ((u >> 16) & 1u);
    return (unsigned short)(u >> 16);
}

// ---- prep: pack weights into bf16 MFMA B-fragment layout in workspace ----
// Block = 16(N) x 32(K) bf16, stored as [n_local*32 + k_local], 512 elems = 1KB.
// Lane l of a wave reads 16B at ((l&15)*32 + (l>>4)*8)*2 -> B[k][n], n=l&15, k=(l>>4)*8+j.
__global__ void moe_prep(const float* __restrict__ w1,   // (4,512,64)
                         const float* __restrict__ w2,   // (4,64,512)
                         const float* __restrict__ b2,   // (4,512)
                         const float* __restrict__ rw,   // (512,4)
                         unsigned short* __restrict__ w1p,
                         unsigned short* __restrict__ w2p,
                         unsigned short* __restrict__ rp) {
    int idx = blockIdx.x * 256 + threadIdx.x;
    if (idx < 131072) {
        // W1' [K=512][N=256], block = kb*16 + cb
        int block = idx >> 9, within = idx & 511;
        int kb = block >> 4, cb = block & 15;
        int n = within >> 5, kl = within & 31;
        int k = kb * 32 + kl;
        int col = cb * 16 + n;          // col in [0,256): e = col>>6, h = col&63
        int e = col >> 6, h = col & 63;
        w1p[idx] = f2bf(w1[(e * 512 + k) * 64 + h]);
    } else if (idx < 131072 + 147456) {
        // W2' [Kpad=288][N=512], block = kb*32 + cb. k in [256,260) = b2 rows, >=260 zero.
        int op = idx - 131072;
        int block = op >> 9, within = op & 511;
        int kb = block >> 5, cb = block & 31;
        int n = within >> 5, kl = within & 31;
        int k = kb * 32 + kl;
        int d = cb * 16 + n;
        float v = 0.f;
        if (k < 256) {
            int e = k >> 6, h = k & 63;
            v = w2[(e * 64 + h) * 512 + d];
        } else if (k < 260) {
            v = b2[(k - 256) * 512 + d];
        }
        w2p[op] = f2bf(v);
    } else if (idx < 131072 + 147456 + 8192) {
        // router W [K=512][N=16] (cols >=4 zero), block = kb
        int op = idx - (131072 + 147456);
        int kb = op >> 9, within = op & 511;
        int n = within >> 5, kl = within & 31;
        int k = kb * 32 + kl;
        float v = (n < 4) ? rw[k * 4 + n] : 0.f;
        rp[op] = f2bf(v);
    }
}

// ---- main fused kernel ----
__global__ __launch_bounds__(256, 2)
void moe_main(const float* __restrict__ x,
              const float* __restrict__ rb,
              const float* __restrict__ b1,
              const unsigned short* __restrict__ w1p,
              const unsigned short* __restrict__ w2p,
              const unsigned short* __restrict__ rp,
              float* __restrict__ out) {
    // X tile [64][XS] bf16 = 66560 B; H tile [64][HS] aliases it after GEMM1.
    __shared__ __align__(16) unsigned short lx[64 * XS];
    __shared__ float lw[64 * 4];

    const int tid  = threadIdx.x;
    const int lane = tid & 63, wv = tid >> 6;
    const int lr = lane & 15, lq = lane >> 4;   // A: m=lr, k=lq*8+j ; B: n=lr ; C: col=lr, row=lq*4+r
    const long t0 = (long)blockIdx.x * 64;

    const float4* xt = (const float4*)(x + t0 * 512);

    // ---- phase A: stage X K-half 0 (cols 0..255) ----
    #pragma unroll
    for (int it = 0; it < 16; ++it) {
        int F = it * 256 + tid;            // f4 index in [64 rows][64 f4 of half-0]
        int row = F >> 6, c = F & 63;
        float4 v = xt[row * 128 + c];
        unsigned int p0 = (unsigned int)f2bf(v.x) | ((unsigned int)f2bf(v.y) << 16);
        unsigned int p1 = (unsigned int)f2bf(v.z) | ((unsigned int)f2bf(v.w) << 16);
        *(uint2*)&lx[row * XS + c * 4] = make_uint2(p0, p1);
    }
    __syncthreads();

    // ---- GEMM1  C1[64][256] = X @ W1'; wave w owns cols [64w,64w+64) = expert w.
    //      Wave w also computes router logits for rows 16w..16w+15 (+1 MFMA/kb). ----
    v4f acc1[4][4];
    v4f accR;
    accR[0] = accR[1] = accR[2] = accR[3] = 0.f;
    #pragma unroll
    for (int mt = 0; mt < 4; ++mt)
        #pragma unroll
        for (int nt = 0; nt < 4; ++nt)
            acc1[mt][nt][0] = acc1[mt][nt][1] = acc1[mt][nt][2] = acc1[mt][nt][3] = 0.f;

    // ---- phase B: GEMM1 kb 0..7 while staging K-half 1 (cols 256..511) ----
    for (int kb = 0; kb < 8; ++kb) {
        // stage 2 float4s of half-1 (writes only cols 256.. — disjoint from reads)
        #pragma unroll
        for (int s = 0; s < 2; ++s) {
            int F = (kb * 2 + s) * 256 + tid;
            int row = F >> 6, c = 64 + (F & 63);
            float4 v = xt[row * 128 + c];
            unsigned int p0 = (unsigned int)f2bf(v.x) | ((unsigned int)f2bf(v.y) << 16);
            unsigned int p1 = (unsigned int)f2bf(v.z) | ((unsigned int)f2bf(v.w) << 16);
            *(uint2*)&lx[row * XS + c * 4] = make_uint2(p0, p1);
        }
        v8s a[4], b[4];
        #pragma unroll
        for (int mt = 0; mt < 4; ++mt)
            a[mt] = *(const v8s*)(const void*)&lx[(16 * mt + lr) * XS + kb * 32 + lq * 8];
        #pragma unroll
        for (int nt = 0; nt < 4; ++nt)
            b[nt] = *(const v8s*)(const void*)&w1p[(size_t)(kb * 16 + wv * 4 + nt) * 512 + lr * 32 + lq * 8];
        v8s ar = *(const v8s*)(const void*)&lx[(16 * wv + lr) * XS + kb * 32 + lq * 8];
        v8s br = *(const v8s*)(const void*)&rp[kb * 512 + lr * 32 + lq * 8];
        accR = __builtin_amdgcn_mfma_f32_16x16x32_bf16(ar, br, accR, 0, 0, 0);
        #pragma unroll
        for (int mt = 0; mt < 4; ++mt)
            #pragma unroll
            for (int nt = 0; nt < 4; ++nt)
                acc1[mt][nt] = __builtin_amdgcn_mfma_f32_16x16x32_bf16(a[mt], b[nt], acc1[mt][nt], 0, 0, 0);
    }
    __syncthreads();   // half-1 staged by all waves

    // ---- phase C: GEMM1 kb 8..15 ----
    for (int kb = 8; kb < 16; ++kb) {
        v8s a[4], b[4];
        #pragma unroll
        for (int mt = 0; mt < 4; ++mt)
            a[mt] = *(const v8s*)(const void*)&lx[(16 * mt + lr) * XS + kb * 32 + lq * 8];
        #pragma unroll
        for (int nt = 0; nt < 4; ++nt)
            b[nt] = *(const v8s*)(const void*)&w1p[(size_t)(kb * 16 + wv * 4 + nt) * 512 + lr * 32 + lq * 8];
        v8s ar = *(const v8s*)(const void*)&lx[(16 * wv + lr) * XS + kb * 32 + lq * 8];
        v8s br = *(const v8s*)(const void*)&rp[kb * 512 + lr * 32 + lq * 8];
        accR = __builtin_amdgcn_mfma_f32_16x16x32_bf16(ar, br, accR, 0, 0, 0);
        #pragma unroll
        for (int mt = 0; mt < 4; ++mt)
            #pragma unroll
            for (int nt = 0; nt < 4; ++nt)
                acc1[mt][nt] = __builtin_amdgcn_mfma_f32_16x16x32_bf16(a[mt], b[nt], acc1[mt][nt], 0, 0, 0);
    }

    // ---- in-register softmax: accR[r] = logit(row = 16wv + lq*4 + r, expert = lr) ----
    {
        float rbv = rb[lane & 3];
        #pragma unroll
        for (int r = 0; r < 4; ++r) {
            float v = accR[r] + rbv;
            float m = fmaxf(v, __shfl_xor(v, 1));
            m = fmaxf(m, __shfl_xor(m, 2));
            float e = expf(v - m);
            float s = e + __shfl_xor(e, 1);
            s += __shfl_xor(s, 2);
            if (lr < 4)
                lw[(16 * wv + lq * 4 + r) * 4 + lr] = e / s;
        }
    }
    __syncthreads();   // all waves done reading X; lw visible; lx may now hold H

    // ---- epilogue: gelu(v+b1)*router_weight -> bf16 H[64][288] ----
    {
        float b1v[4];
        #pragma unroll
        for (int nt = 0; nt < 4; ++nt) b1v[nt] = b1[wv * 64 + nt * 16 + lr];
        #pragma unroll
        for (int mt = 0; mt < 4; ++mt) {
            #pragma unroll
            for (int r = 0; r < 4; ++r) {
                int row = 16 * mt + lq * 4 + r;
                float wt = lw[row * 4 + wv];
                #pragma unroll
                for (int nt = 0; nt < 4; ++nt) {
                    float v = acc1[mt][nt][r] + b1v[nt];
                    float g = 0.5f * v * (1.f + erff(v * 0.70710678118f)) * wt;
                    lx[row * HS + wv * 64 + nt * 16 + lr] = f2bf(g);
                }
            }
        }
        // append router-weight cols (k=256..259) and zero pad (260..287)
        int r = tid >> 2, e = tid & 3;
        lx[r * HS + 256 + e] = f2bf(lw[tid]);
        #pragma unroll
        for (int i = 0; i < 7; ++i)
            lx[r * HS + 260 + e + 4 * i] = 0;
    }
    __syncthreads();

    // ---- GEMM2  OUT[64][512] = H[64][288] @ W2'; wave w owns cols [128w,128w+128) ----
    v4f acc2[4][8];
    #pragma unroll
    for (int mt = 0; mt < 4; ++mt)
        #pragma unroll
        for (int nt = 0; nt < 8; ++nt)
            acc2[mt][nt][0] = acc2[mt][nt][1] = acc2[mt][nt][2] = acc2[mt][nt][3] = 0.f;

    for (int kb = 0; kb < 9; ++kb) {
        v8s a[4], b[8];
        #pragma unroll
        for (int mt = 0; mt < 4; ++mt)
            a[mt] = *(const v8s*)(const void*)&lx[(16 * mt + lr) * HS + kb * 32 + lq * 8];
        #pragma unroll
        for (int nt = 0; nt < 8; ++nt)
            b[nt] = *(const v8s*)(const void*)&w2p[(size_t)(kb * 32 + wv * 8 + nt) * 512 + lr * 32 + lq * 8];
        #pragma unroll
        for (int mt = 0; mt < 4; ++mt)
            #pragma unroll
            for (int nt = 0; nt < 8; ++nt)
                acc2[mt][nt] = __builtin_amdgcn_mfma_f32_16x16x32_bf16(a[mt], b[nt], acc2[mt][nt], 0, 0, 0);
    }

    float* ot = out + t0 * 512;
    #pragma unroll
    for (int mt = 0; mt < 4; ++mt)
        #pragma unroll
        for (int nt = 0; nt < 8; ++nt)
            #pragma unroll
            for (int r = 0; r < 4; ++r) {
                int row = 16 * mt + lq * 4 + r;
                int col = 128 * wv + 16 * nt + lr;
                ot[row * 512 + col] = acc2[mt][nt][r];
            }
}

extern "C" void kernel_launch(void* const* d_in, const int* in_sizes, int n_in,
                              void* d_out, int out_size, void* d_ws, size_t ws_size,
                              hipStream_t stream) {
    const float* x  = (const float*)d_in[0];
    const float* rw = (const float*)d_in[1];
    const float* rb = (const float*)d_in[2];
    const float* w1 = (const float*)d_in[3];
    const float* b1 = (const float*)d_in[4];
    const float* w2 = (const float*)d_in[5];
    const float* b2 = (const float*)d_in[6];

    unsigned short* w1p = (unsigned short*)d_ws;      // 131072 elems
    unsigned short* w2p = w1p + 131072;               // 147456 elems
    unsigned short* rp  = w2p + 147456;               // 8192 elems  (total ~573 KB)

    moe_prep<<<1120, 256, 0, stream>>>(w1, w2, b2, rw, w1p, w2p, rp);
    moe_main<<<512, 256, 0, stream>>>(x, rb, b1, w1p, w2p, rp, (float*)d_out);
}

// Round 5
// 142.509 us; speedup vs baseline: 1.2046x; 1.0149x over previous
//
#include <hip/hip_runtime.h>
#include <hip/hip_bf16.h>
#include <math.h>

// TinyMoE: out = sum_e softmax(x@Wr)[e] * (gelu(x@w1[e]+b1[e]) @ w2[e] + b2[e])
// Two dense GEMMs: [32768x512]@[512x256] -> gelu/scale -> @[256x512(+b2 rows)]
// bf16 MFMA (16x16x32), fp32 router/softmax/gelu.
// v6: 128 tokens per WG, 512 threads (8 waves), 1 block/CU (LDS 133KB).
//     Per-wave structure identical to v1/v5 (acc1[4][4], acc2[4][8], ~250 regs,
//     no spill) but half the blocks -> half the per-block weight L2 re-fetch
//     (262->134 MB) and half the fixed costs. #pragma unroll 2 on K-loops gives
//     the scheduler a window to hoist next-kb weight loads over current MFMAs.
//     Wave w: mh=w>>2 (row half), e=w&3 (expert / col quarter). Router fold:
//     wave w computes logit rows 16w..16w+15.

typedef short v8s __attribute__((ext_vector_type(8)));
typedef float v4f __attribute__((ext_vector_type(4)));

#define XS 520   // X LDS row stride (bf16 elems): 512 + 8 pad
#define HS 296   // H LDS row stride: 288 (=256 + 4 b2-weight rows + 28 zero pad) + 8 pad

__device__ __forceinline__ unsigned short f2bf(float f) {
    unsigned int u = __builtin_bit_cast(unsigned int, f);
    u += 0x7fffu + ((u >> 16) & 1u);
    return (unsigned short)(u >> 16);
}

// ---- prep: pack weights into bf16 MFMA B-fragment layout in workspace ----
// Block = 16(N) x 32(K) bf16, stored as [n_local*32 + k_local], 512 elems = 1KB.
// Lane l of a wave reads 16B at ((l&15)*32 + (l>>4)*8)*2 -> B[k][n], n=l&15, k=(l>>4)*8+j.
__global__ void moe_prep(const float* __restrict__ w1,   // (4,512,64)
                         const float* __restrict__ w2,   // (4,64,512)
                         const float* __restrict__ b2,   // (4,512)
                         const float* __restrict__ rw,   // (512,4)
                         unsigned short* __restrict__ w1p,
                         unsigned short* __restrict__ w2p,
                         unsigned short* __restrict__ rp) {
    int idx = blockIdx.x * 256 + threadIdx.x;
    if (idx < 131072) {
        // W1' [K=512][N=256], block = kb*16 + cb
        int block = idx >> 9, within = idx & 511;
        int kb = block >> 4, cb = block & 15;
        int n = within >> 5, kl = within & 31;
        int k = kb * 32 + kl;
        int col = cb * 16 + n;          // col in [0,256): e = col>>6, h = col&63
        int e = col >> 6, h = col & 63;
        w1p[idx] = f2bf(w1[(e * 512 + k) * 64 + h]);
    } else if (idx < 131072 + 147456) {
        // W2' [Kpad=288][N=512], block = kb*32 + cb. k in [256,260) = b2 rows, >=260 zero.
        int op = idx - 131072;
        int block = op >> 9, within = op & 511;
        int kb = block >> 5, cb = block & 31;
        int n = within >> 5, kl = within & 31;
        int k = kb * 32 + kl;
        int d = cb * 16 + n;
        float v = 0.f;
        if (k < 256) {
            int e = k >> 6, h = k & 63;
            v = w2[(e * 64 + h) * 512 + d];
        } else if (k < 260) {
            v = b2[(k - 256) * 512 + d];
        }
        w2p[op] = f2bf(v);
    } else if (idx < 131072 + 147456 + 8192) {
        // router W [K=512][N=16] (cols >=4 zero), block = kb
        int op = idx - (131072 + 147456);
        int kb = op >> 9, within = op & 511;
        int n = within >> 5, kl = within & 31;
        int k = kb * 32 + kl;
        float v = (n < 4) ? rw[k * 4 + n] : 0.f;
        rp[op] = f2bf(v);
    }
}

// ---- main fused kernel ----
__global__ __launch_bounds__(512, 2)
void moe_main(const float* __restrict__ x,
              const float* __restrict__ rb,
              const float* __restrict__ b1,
              const unsigned short* __restrict__ w1p,
              const unsigned short* __restrict__ w2p,
              const unsigned short* __restrict__ rp,
              float* __restrict__ out) {
    // X tile [128][XS] bf16 = 133120 B; H tile [128][HS] aliases it after GEMM1.
    __shared__ __align__(16) unsigned short lx[128 * XS];
    __shared__ float lw[128 * 4];

    const int tid  = threadIdx.x;
    const int lane = tid & 63, wv = tid >> 6;          // wv 0..7
    const int lr = lane & 15, lq = lane >> 4;          // A: m=lr, k=lq*8+j ; B: n=lr ; C: col=lr, row=lq*4+r
    const int mh = wv >> 2, we4 = wv & 3;              // row-half, expert/col-quarter
    const long t0 = (long)blockIdx.x * 128;

    const float4* xt = (const float4*)(x + t0 * 512);

    // ---- phase A: stage X K-half 0 (cols 0..255) ----
    #pragma unroll
    for (int it = 0; it < 16; ++it) {
        int F = it * 512 + tid;            // f4 index in [128 rows][64 f4 of half-0]
        int row = F >> 6, c = F & 63;
        float4 v = xt[row * 128 + c];
        unsigned int p0 = (unsigned int)f2bf(v.x) | ((unsigned int)f2bf(v.y) << 16);
        unsigned int p1 = (unsigned int)f2bf(v.z) | ((unsigned int)f2bf(v.w) << 16);
        *(uint2*)&lx[row * XS + c * 4] = make_uint2(p0, p1);
    }
    __syncthreads();

    // ---- GEMM1  C1[128][256] = X @ W1'; wave w: rows [64mh,64mh+64), cols [64we4,64we4+64)
    //      = expert we4. Wave w also computes router logits for rows 16w..16w+15. ----
    v4f acc1[4][4];
    v4f accR;
    accR[0] = accR[1] = accR[2] = accR[3] = 0.f;
    #pragma unroll
    for (int mt = 0; mt < 4; ++mt)
        #pragma unroll
        for (int nt = 0; nt < 4; ++nt)
            acc1[mt][nt][0] = acc1[mt][nt][1] = acc1[mt][nt][2] = acc1[mt][nt][3] = 0.f;

    // ---- phase B: GEMM1 kb 0..7 while staging K-half 1 (cols 256..511) ----
    for (int kb = 0; kb < 8; ++kb) {
        // stage 2 float4s of half-1 (writes only cols 256.. — disjoint from all reads)
        #pragma unroll
        for (int s = 0; s < 2; ++s) {
            int F = (kb * 2 + s) * 512 + tid;
            int row = F >> 6, c = 64 + (F & 63);
            float4 v = xt[row * 128 + c];
            unsigned int p0 = (unsigned int)f2bf(v.x) | ((unsigned int)f2bf(v.y) << 16);
            unsigned int p1 = (unsigned int)f2bf(v.z) | ((unsigned int)f2bf(v.w) << 16);
            *(uint2*)&lx[row * XS + c * 4] = make_uint2(p0, p1);
        }
        v8s a[4], b[4];
        #pragma unroll
        for (int nt = 0; nt < 4; ++nt)
            b[nt] = *(const v8s*)(const void*)&w1p[(size_t)(kb * 16 + we4 * 4 + nt) * 512 + lr * 32 + lq * 8];
        #pragma unroll
        for (int mt = 0; mt < 4; ++mt)
            a[mt] = *(const v8s*)(const void*)&lx[(64 * mh + 16 * mt + lr) * XS + kb * 32 + lq * 8];
        v8s ar = *(const v8s*)(const void*)&lx[(16 * wv + lr) * XS + kb * 32 + lq * 8];
        v8s br = *(const v8s*)(const void*)&rp[kb * 512 + lr * 32 + lq * 8];
        accR = __builtin_amdgcn_mfma_f32_16x16x32_bf16(ar, br, accR, 0, 0, 0);
        #pragma unroll
        for (int mt = 0; mt < 4; ++mt)
            #pragma unroll
            for (int nt = 0; nt < 4; ++nt)
                acc1[mt][nt] = __builtin_amdgcn_mfma_f32_16x16x32_bf16(a[mt], b[nt], acc1[mt][nt], 0, 0, 0);
    }
    __syncthreads();   // half-1 staged by all waves

    // ---- phase C: GEMM1 kb 8..15 (unroll-2 window lets next-kb loads hoist) ----
    #pragma unroll 2
    for (int kb = 8; kb < 16; ++kb) {
        v8s a[4], b[4];
        #pragma unroll
        for (int nt = 0; nt < 4; ++nt)
            b[nt] = *(const v8s*)(const void*)&w1p[(size_t)(kb * 16 + we4 * 4 + nt) * 512 + lr * 32 + lq * 8];
        #pragma unroll
        for (int mt = 0; mt < 4; ++mt)
            a[mt] = *(const v8s*)(const void*)&lx[(64 * mh + 16 * mt + lr) * XS + kb * 32 + lq * 8];
        v8s ar = *(const v8s*)(const void*)&lx[(16 * wv + lr) * XS + kb * 32 + lq * 8];
        v8s br = *(const v8s*)(const void*)&rp[kb * 512 + lr * 32 + lq * 8];
        accR = __builtin_amdgcn_mfma_f32_16x16x32_bf16(ar, br, accR, 0, 0, 0);
        #pragma unroll
        for (int mt = 0; mt < 4; ++mt)
            #pragma unroll
            for (int nt = 0; nt < 4; ++nt)
                acc1[mt][nt] = __builtin_amdgcn_mfma_f32_16x16x32_bf16(a[mt], b[nt], acc1[mt][nt], 0, 0, 0);
    }

    // ---- in-register softmax: accR[r] = logit(row = 16wv + lq*4 + r, expert = lr) ----
    {
        float rbv = rb[lane & 3];
        #pragma unroll
        for (int r = 0; r < 4; ++r) {
            float v = accR[r] + rbv;
            float m = fmaxf(v, __shfl_xor(v, 1));
            m = fmaxf(m, __shfl_xor(m, 2));
            float e = expf(v - m);
            float s = e + __shfl_xor(e, 1);
            s += __shfl_xor(s, 2);
            if (lr < 4)
                lw[(16 * wv + lq * 4 + r) * 4 + lr] = e / s;
        }
    }
    __syncthreads();   // all waves done reading X; lw visible; lx may now hold H

    // ---- epilogue: gelu(v+b1)*router_weight -> bf16 H[128][288] ----
    {
        float b1v[4];
        #pragma unroll
        for (int nt = 0; nt < 4; ++nt) b1v[nt] = b1[we4 * 64 + nt * 16 + lr];
        #pragma unroll
        for (int mt = 0; mt < 4; ++mt) {
            #pragma unroll
            for (int r = 0; r < 4; ++r) {
                int row = 64 * mh + 16 * mt + lq * 4 + r;
                float wt = lw[row * 4 + we4];
                #pragma unroll
                for (int nt = 0; nt < 4; ++nt) {
                    float v = acc1[mt][nt][r] + b1v[nt];
                    float g = 0.5f * v * (1.f + erff(v * 0.70710678118f)) * wt;
                    lx[row * HS + we4 * 64 + nt * 16 + lr] = f2bf(g);
                }
            }
        }
        // append router-weight cols (k=256..259) and zero pad (260..287)
        int r = tid >> 2, e = tid & 3;        // 512 threads cover 128 rows x 4 experts
        lx[r * HS + 256 + e] = f2bf(lw[r * 4 + e]);
        #pragma unroll
        for (int i = 0; i < 7; ++i)
            lx[r * HS + 260 + e + 4 * i] = 0;
    }
    __syncthreads();

    // ---- GEMM2  OUT[128][512] = H[128][288] @ W2'; wave w: rows [64mh,..), cols [128we4,..) ----
    v4f acc2[4][8];
    #pragma unroll
    for (int mt = 0; mt < 4; ++mt)
        #pragma unroll
        for (int nt = 0; nt < 8; ++nt)
            acc2[mt][nt][0] = acc2[mt][nt][1] = acc2[mt][nt][2] = acc2[mt][nt][3] = 0.f;

    #pragma unroll 2
    for (int kb = 0; kb < 9; ++kb) {
        v8s a[4], b[8];
        #pragma unroll
        for (int nt = 0; nt < 8; ++nt)
            b[nt] = *(const v8s*)(const void*)&w2p[(size_t)(kb * 32 + we4 * 8 + nt) * 512 + lr * 32 + lq * 8];
        #pragma unroll
        for (int mt = 0; mt < 4; ++mt)
            a[mt] = *(const v8s*)(const void*)&lx[(64 * mh + 16 * mt + lr) * HS + kb * 32 + lq * 8];
        #pragma unroll
        for (int mt = 0; mt < 4; ++mt)
            #pragma unroll
            for (int nt = 0; nt < 8; ++nt)
                acc2[mt][nt] = __builtin_amdgcn_mfma_f32_16x16x32_bf16(a[mt], b[nt], acc2[mt][nt], 0, 0, 0);
    }

    float* ot = out + t0 * 512;
    #pragma unroll
    for (int mt = 0; mt < 4; ++mt)
        #pragma unroll
        for (int nt = 0; nt < 8; ++nt)
            #pragma unroll
            for (int r = 0; r < 4; ++r) {
                int row = 64 * mh + 16 * mt + lq * 4 + r;
                int col = 128 * we4 + 16 * nt + lr;
                ot[row * 512 + col] = acc2[mt][nt][r];
            }
}

extern "C" void kernel_launch(void* const* d_in, const int* in_sizes, int n_in,
                              void* d_out, int out_size, void* d_ws, size_t ws_size,
                              hipStream_t stream) {
    const float* x  = (const float*)d_in[0];
    const float* rw = (const float*)d_in[1];
    const float* rb = (const float*)d_in[2];
    const float* w1 = (const float*)d_in[3];
    const float* b1 = (const float*)d_in[4];
    const float* w2 = (const float*)d_in[5];
    const float* b2 = (const float*)d_in[6];

    unsigned short* w1p = (unsigned short*)d_ws;      // 131072 elems
    unsigned short* w2p = w1p + 131072;               // 147456 elems
    unsigned short* rp  = w2p + 147456;               // 8192 elems  (total ~573 KB)

    moe_prep<<<1120, 256, 0, stream>>>(w1, w2, b2, rw, w1p, w2p, rp);
    moe_main<<<256, 512, 0, stream>>>(x, rb, b1, w1p, w2p, rp, (float*)d_out);
}